// Round 9
// baseline (746.594 us; speedup 1.0000x reference)
//
#include <hip/hip_runtime.h>
#include <cstdint>

// ---------------------------------------------------------------------------
// VAE attention block: GN -> QKV 1x1 conv -> softmax(QK^T) V -> proj + x
// B=4, H=W=64 (N=4096 pixels/batch), C=512, GROUPS=32
// R11 (3rd submit; R7/R8 benches were GPU-broker failures — never measured):
// flash_attn v5 — split-KV occupancy (v4 post-mortem: halving QBLK doubled
// per-CU LDS traffic; occupancy lever right, tile shrink wrong).
//   - 512 blocks: (batch, mt, half). QBLK stays 64; each block sweeps 16 of
//     32 KV tiles. Per-CU LDS/MFMA work identical to v3; 2 blocks/CU.
//   - no-max softmax => partials combine LINEARLY: O=O0+O1, l=l0+l1 (exact).
//     flash writes f32 partials op[2][16384][512] + lp[2][16384]; a small
//     combine kernel normalizes to bf16 ao (~13 us).
//   - sK single-buffered 64 KB (2-block residency); stage(t+1) issued after
//     the P-barrier, drain covered by PV + sibling block (m114 overlap).
//   - T5 setprio(1) around MFMA clusters (helps once phases diverge, m191).
//   - launch_bounds(512,4): VGPR capped 128 (16 waves/CU).
// ---------------------------------------------------------------------------

typedef __bf16 bf16_t;
typedef bf16_t bf16x8 __attribute__((ext_vector_type(8)));
typedef float floatx4 __attribute__((ext_vector_type(4)));
typedef int v8i __attribute__((ext_vector_type(8)));

__device__ __forceinline__ uint16_t f2b(float f) {
    uint32_t u = __builtin_bit_cast(uint32_t, f);
    u += 0x7fffu + ((u >> 16) & 1u);
    return (uint16_t)(u >> 16);
}
__device__ __forceinline__ float b2f(uint16_t h) {
    uint32_t u = ((uint32_t)h) << 16;
    return __builtin_bit_cast(float, u);
}
// pack 4 floats -> 4 fp8 e4m3 bytes (byte 0 = first arg)
__device__ __forceinline__ unsigned pk_fp8x4(float a, float b, float c, float d) {
    int w = __builtin_amdgcn_cvt_pk_fp8_f32(a, b, 0, false);
    w = __builtin_amdgcn_cvt_pk_fp8_f32(c, d, w, true);
    return (unsigned)w;
}

__device__ __forceinline__ void lds_copy16(void* lds, const void* glob) {
    __builtin_amdgcn_global_load_lds(
        (__attribute__((address_space(1))) void*)(void*)glob,
        (__attribute__((address_space(3))) void*)lds,
        16, 0, 0);
}

// ---------------------------------------------------------------------------
// GroupNorm stats: one block per (batch, group).
// ---------------------------------------------------------------------------
__global__ __launch_bounds__(256) void gn_stats(const float* __restrict__ x,
                                                float* __restrict__ stats) {
    const int bg = blockIdx.x;            // 0..127
    const int tid = threadIdx.x;
    const int b = bg >> 5, g = bg & 31;
    const float* base = x + (long)b * (4096L * 512) + g * 16;
    float s = 0.f, sq = 0.f;
    #pragma unroll 8
    for (int i = 0; i < 64; i++) {
        int idx4 = tid + i * 256;          // float4 index within group
        int pixel = idx4 >> 2, c4 = idx4 & 3;
        const float4 v = *(const float4*)(base + (long)pixel * 512 + c4 * 4);
        s += v.x + v.y + v.z + v.w;
        sq += v.x * v.x + v.y * v.y + v.z * v.z + v.w * v.w;
    }
    #pragma unroll
    for (int off = 32; off > 0; off >>= 1) {
        s += __shfl_down(s, off);
        sq += __shfl_down(sq, off);
    }
    __shared__ float rs[4], rq[4];
    const int lane = tid & 63, w = tid >> 6;
    if (lane == 0) { rs[w] = s; rq[w] = sq; }
    __syncthreads();
    if (tid == 0) {
        float S = rs[0] + rs[1] + rs[2] + rs[3];
        float Q = rq[0] + rq[1] + rq[2] + rq[3];
        float mean = S * (1.f / 65536.f);
        float var = Q * (1.f / 65536.f) - mean * mean;
        stats[bg * 2 + 0] = mean;
        stats[bg * 2 + 1] = rsqrtf(var + 1e-5f);
    }
}

// ---------------------------------------------------------------------------
// GroupNorm apply: h_bf16 = (x-mean)*rstd*gamma + beta.  4 elems/thread.
// ---------------------------------------------------------------------------
__global__ __launch_bounds__(256) void gn_apply(const float* __restrict__ x,
                                                const float* __restrict__ stats,
                                                const float* __restrict__ gamma,
                                                const float* __restrict__ beta,
                                                uint16_t* __restrict__ h) {
    const long idx4 = (long)blockIdx.x * 256 + threadIdx.x;   // 0..2097151
    const long e0 = idx4 * 4;
    const int c = (int)(e0 & 511);
    const int b = (int)(e0 >> 21);                            // 4096*512 = 2^21
    const float2 st = ((const float2*)stats)[b * 32 + (c >> 4)];
    const float4 v = ((const float4*)x)[idx4];
    const float4 gm = ((const float4*)gamma)[c >> 2];
    const float4 bt = ((const float4*)beta)[c >> 2];
    union { ushort4 u; uint16_t s[4]; } o;
    o.s[0] = f2b((v.x - st.x) * st.y * gm.x + bt.x);
    o.s[1] = f2b((v.y - st.x) * st.y * gm.y + bt.y);
    o.s[2] = f2b((v.z - st.x) * st.y * gm.z + bt.z);
    o.s[3] = f2b((v.w - st.x) * st.y * gm.w + bt.w);
    ((ushort4*)h)[idx4] = o.u;
}

// ---------------------------------------------------------------------------
// Cast+transpose weights: wT[d][c] = bf16(w[c][d]), 512x512, 64x64 LDS tiles.
// ---------------------------------------------------------------------------
__global__ __launch_bounds__(256) void wcast_transpose(const float* __restrict__ w0,
                                                       const float* __restrict__ w1,
                                                       const float* __restrict__ w2,
                                                       const float* __restrict__ w3,
                                                       uint16_t* __restrict__ out) {
    const float* ws[4] = {w0, w1, w2, w3};
    const float* w = ws[blockIdx.z];
    uint16_t* o = out + (long)blockIdx.z * 512 * 512;
    __shared__ uint16_t t[64][65];
    const int nb = blockIdx.x * 64, kb = blockIdx.y * 64;
    const int lc = threadIdx.x & 63, lg = threadIdx.x >> 6;
    #pragma unroll
    for (int i = 0; i < 16; i++) {
        int r = lg * 16 + i;
        t[lc][r] = f2b(w[(long)(kb + r) * 512 + nb + lc]);   // t[n_loc][k_loc]
    }
    __syncthreads();
    #pragma unroll
    for (int i = 0; i < 16; i++) {
        int r = lg * 16 + i;
        o[(long)(nb + r) * 512 + kb + lc] = t[r][lc];        // wT[n][k]
    }
}

// ---------------------------------------------------------------------------
// Fused QKV GEMM (bf16 MFMA): [16384,512] x [1536,512]^T.  Grid (12, 128).
// Outputs fp8 e4m3: cols 0-511 -> q, 512-1023 -> k, 1024-1535 -> v stored
// TRANSPOSED (vt[b][ch][pix]).  No scale on q (moved to flash epilogue).
// ---------------------------------------------------------------------------
__global__ __launch_bounds__(256) void qkv_gemm(const uint16_t* __restrict__ h,
                                                const uint16_t* __restrict__ wT,
                                                const float* __restrict__ bq,
                                                const float* __restrict__ bk,
                                                const float* __restrict__ bv,
                                                uint8_t* __restrict__ q,
                                                uint8_t* __restrict__ k,
                                                uint8_t* __restrict__ vt) {
    __shared__ __align__(16) uint16_t smem[128 * 136];
    uint16_t* sA = smem;
    uint16_t* sB = smem + 8192;

    const int tid = threadIdx.x;
    const long m0 = (long)blockIdx.y * 128;
    const int n0 = blockIdx.x * 128;

    const int lane = tid & 63;
    const int wave = tid >> 6;
    const int wm = (wave & 1) * 64;
    const int wn = (wave >> 1) * 64;
    const int fr = lane & 15;
    const int fh = lane >> 4;
    const int sw = fr & 7;

    floatx4 acc[4][4];
    #pragma unroll
    for (int i = 0; i < 4; i++)
        #pragma unroll
        for (int j = 0; j < 4; j++) acc[i][j] = (floatx4){0.f, 0.f, 0.f, 0.f};

    for (int kt = 0; kt < 512; kt += 64) {
        __syncthreads();
        #pragma unroll
        for (int i = 0; i < 4; i++) {
            const int c = i * 256 + tid;
            const int row = c >> 3;
            const int gj = (c & 7) ^ (row & 7);
            lds_copy16(&sA[c * 8], h + (m0 + row) * 512L + kt + gj * 8);
            lds_copy16(&sB[c * 8], wT + (n0 + row) * 512L + kt + gj * 8);
        }
        __syncthreads();
        #pragma unroll
        for (int kk = 0; kk < 64; kk += 32) {
            const int jx = ((fh + (kk >> 3)) ^ sw) * 8;
            bf16x8 av[4], bv_[4];
            #pragma unroll
            for (int mi = 0; mi < 4; mi++)
                av[mi] = *(const bf16x8*)&sA[(wm + mi * 16 + fr) * 64 + jx];
            #pragma unroll
            for (int ni = 0; ni < 4; ni++)
                bv_[ni] = *(const bf16x8*)&sB[(wn + ni * 16 + fr) * 64 + jx];
            #pragma unroll
            for (int mi = 0; mi < 4; mi++)
                #pragma unroll
                for (int ni = 0; ni < 4; ni++)
                    acc[mi][ni] = __builtin_amdgcn_mfma_f32_16x16x32_bf16(
                        av[mi], bv_[ni], acc[mi][ni], 0, 0, 0);
        }
    }

    const int quad = lane >> 4;
    const int w = n0 >> 9;          // 0=q, 1=k, 2=v(T)
    const int nc = n0 & 511;
    const float* bias = (w == 0) ? bq : (w == 1) ? bk : bv;
    __syncthreads();
    if (w < 2) {
        // repack bf16 rows, then fp8-convert during the coalesced store
        #pragma unroll
        for (int ni = 0; ni < 4; ni++) {
            const int col_l = wn + ni * 16 + fr;
            const float bb = bias[nc + col_l];
            #pragma unroll
            for (int mi = 0; mi < 4; mi++) {
                #pragma unroll
                for (int r = 0; r < 4; r++) {
                    const int row_l = wm + mi * 16 + quad * 4 + r;
                    smem[row_l * 136 + col_l] = f2b(acc[mi][ni][r] + bb);
                }
            }
        }
        __syncthreads();
        uint8_t* out = (w == 0) ? q : k;
        #pragma unroll
        for (int it = 0; it < 8; it++) {
            const int row_l = it * 16 + (tid >> 4);
            const int c0 = (tid & 15) * 8;
            const uint4 d = *(const uint4*)&smem[row_l * 136 + c0];
            const uint16_t* e = (const uint16_t*)&d;
            uint2 o;
            o.x = pk_fp8x4(b2f(e[0]), b2f(e[1]), b2f(e[2]), b2f(e[3]));
            o.y = pk_fp8x4(b2f(e[4]), b2f(e[5]), b2f(e[6]), b2f(e[7]));
            *(uint2*)&out[(m0 + row_l) * 512 + nc + c0] = o;
        }
    } else {
        // transposed fp8 repack: s8[ch][pix], byte stride 144 (16B-aligned)
        uint8_t* s8 = (uint8_t*)smem;
        #pragma unroll
        for (int ni = 0; ni < 4; ni++) {
            const int ch_l = wn + ni * 16 + fr;
            const float bb = bias[nc + ch_l];
            #pragma unroll
            for (int mi = 0; mi < 4; mi++) {
                const int pix0 = wm + mi * 16 + quad * 4;
                *(unsigned*)&s8[ch_l * 144 + pix0] =
                    pk_fp8x4(acc[mi][ni][0] + bb, acc[mi][ni][1] + bb,
                             acc[mi][ni][2] + bb, acc[mi][ni][3] + bb);
            }
        }
        __syncthreads();
        const long b = m0 >> 12;
        const int pixb = (int)(m0 & 4095);
        uint8_t* vtb = vt + b * (512L * 4096);
        #pragma unroll
        for (int it = 0; it < 4; it++) {
            const int ch_l = it * 32 + (tid >> 3);
            const int p0 = (tid & 7) * 16;
            *(uint4*)&vtb[(long)(nc + ch_l) * 4096 + pixb + p0] =
                *(const uint4*)&s8[ch_l * 144 + p0];
        }
    }
}

// ---------------------------------------------------------------------------
// Fused flash attention v5 (fp8 MX MFMA, unit scales), SPLIT-KV:
// 512 blocks = (batch, mt, half); each sweeps 16 of 32 KV tiles for its
// 64 Q-rows and writes UNNORMALIZED f32 partials op[half][pix][ch] and
// row-sums lp[half][pix]. QBLK=64, 8 waves; sK single-buffered 64 KB
// (2 blocks/CU). S wave tile 32x32, Q in regs, V global->reg, P via 8 KB
// swizzled LDS. setprio(1) around MFMA clusters.
// ---------------------------------------------------------------------------
__global__ __launch_bounds__(512, 4) void flash_attn(const uint8_t* __restrict__ q8,
                                                     const uint8_t* __restrict__ k8,
                                                     const uint8_t* __restrict__ vt8,
                                                     float* __restrict__ op,
                                                     float* __restrict__ lp) {
    __shared__ __align__(16) uint8_t sK[65536];         // [kt][row][128B]
    __shared__ __align__(16) uint8_t Pl[8192];          // fp8 P tile (swizzled)
    __shared__ float lpart[8][32];

    const int tid = threadIdx.x;
    const int lane = tid & 63;
    const int wave = tid >> 6;
    const int fr = lane & 15;
    const int quad = lane >> 4;
    const int sw = fr & 7;

    // XCD-chunked swizzle; both halves of a Q-tile land on the same XCD,
    // K/V working set per XCD = one batch (4 MB) -> L2-resident.
    const int lb = ((blockIdx.x & 7) << 6) | (blockIdx.x >> 3);
    const int half = lb & 1;
    const int qt = lb >> 1;                  // 0..255
    const int batch = qt >> 6;
    const int mt = qt & 63;
    const long qbase = (long)batch * 4096 + mt * 64;   // row base in q8
    const int t0 = half * 16;

    const int wr = wave >> 2;           // S row-group (2 x 32 rows)
    const int wcg = wave & 3;           // S col-group (4 x 32 cols)
    const int wm = wr * 32;
    const int wc = wcg * 32;
    const float qscale = 0.06375871540654937f;   // log2(e)/sqrt(512)

    // Q fragments: rows wm+mi*16+fr, bytes kt*128 + quad*32..+31 (in regs)
    v8i aQ[2][4];
    #pragma unroll
    for (int mi = 0; mi < 2; mi++) {
        const uint8_t* qp = q8 + (qbase + wm + mi * 16 + fr) * 512 + quad * 32;
        #pragma unroll
        for (int kt = 0; kt < 4; kt++) {
            const uint4 lo = *(const uint4*)(qp + kt * 128);
            const uint4 hi = *(const uint4*)(qp + kt * 128 + 16);
            aQ[mi][kt] = (v8i){(int)lo.x, (int)lo.y, (int)lo.z, (int)lo.w,
                               (int)hi.x, (int)hi.y, (int)hi.z, (int)hi.w};
        }
    }
    const uint8_t* kbb = k8 + (long)batch * (4096L * 512);
    const uint8_t* vrow = vt8 + (long)batch * (512L * 4096) +
                          (long)(wave * 64 + fr) * 4096 + quad * 32;

    floatx4 oacc[4][4];                 // [mi][ni]: rows mi*16.., ch wave*64+ni*16..
    #pragma unroll
    for (int i = 0; i < 4; i++)
        #pragma unroll
        for (int j = 0; j < 4; j++) oacc[i][j] = (floatx4){0.f, 0.f, 0.f, 0.f};
    float lsum[2][4];
    #pragma unroll
    for (int i = 0; i < 2; i++)
        #pragma unroll
        for (int r = 0; r < 4; r++) lsum[i][r] = 0.f;

#define STAGE(t_)                                                              \
    do {                                                                       \
        const uint8_t* kb = kbb + (long)(t_) * (128L * 512);                   \
        _Pragma("unroll")                                                      \
        for (int i = 0; i < 8; i++) {                                          \
            const int chunk = i * 512 + tid;                                   \
            const int kt = chunk >> 10;                                        \
            const int c = chunk & 1023;                                        \
            const int row = c >> 3;                                            \
            const int gj = (c & 7) ^ (row & 7);                                \
            lds_copy16(&sK[kt * 16384 + c * 16],                               \
                       kb + row * 512 + kt * 128 + gj * 16);                   \
        }                                                                      \
    } while (0)

    STAGE(t0);

    for (int tt = 0; tt < 16; tt++) {
        const int t = t0 + tt;
        __syncthreads();   // A: stage(t) drained -> sK ready; Pl free
        // ---- V(t) fragments (reg-destined; latency hides under S) ----
        v8i bV[4];
        #pragma unroll
        for (int ni = 0; ni < 4; ni++) {
            const uint8_t* vp = vrow + (long)ni * (16L * 4096) + t * 128;
            const uint4 lo = *(const uint4*)vp;
            const uint4 hi = *(const uint4*)(vp + 16);
            bV[ni] = (v8i){(int)lo.x, (int)lo.y, (int)lo.z, (int)lo.w,
                           (int)hi.x, (int)hi.y, (int)hi.z, (int)hi.w};
        }
        // ---- S = Q @ K_tile^T (32x32 per wave) from sK ----
        floatx4 sacc[2][2];
        #pragma unroll
        for (int mi = 0; mi < 2; mi++)
            #pragma unroll
            for (int ni = 0; ni < 2; ni++) sacc[mi][ni] = (floatx4){0.f, 0.f, 0.f, 0.f};
        __builtin_amdgcn_s_setprio(1);
        #pragma unroll
        for (int kt = 0; kt < 4; kt++) {
            v8i bK[2];
            #pragma unroll
            for (int ni = 0; ni < 2; ni++) {
                const int row = wc + ni * 16 + fr;
                const uint8_t* base = &sK[kt * 16384 + row * 128];
                const uint4 lo = *(const uint4*)(base + (((2 * quad) ^ sw) << 4));
                const uint4 hi = *(const uint4*)(base + (((2 * quad + 1) ^ sw) << 4));
                bK[ni] = (v8i){(int)lo.x, (int)lo.y, (int)lo.z, (int)lo.w,
                               (int)hi.x, (int)hi.y, (int)hi.z, (int)hi.w};
            }
            #pragma unroll
            for (int mi = 0; mi < 2; mi++)
                #pragma unroll
                for (int ni = 0; ni < 2; ni++)
                    sacc[mi][ni] = __builtin_amdgcn_mfma_scale_f32_16x16x128_f8f6f4(
                        aQ[mi][kt], bK[ni], sacc[mi][ni], 0, 0, 0, 0x7f7f7f7fu, 0,
                        0x7f7f7f7fu);
        }
        __builtin_amdgcn_s_setprio(0);
        // ---- p = exp2(s*scale); accumulate l; pack fp8; scatter to Pl ----
        #pragma unroll
        for (int mi = 0; mi < 2; mi++) {
            #pragma unroll
            for (int ni = 0; ni < 2; ni++) {
                const float p0 = exp2f(sacc[mi][ni][0] * qscale);
                const float p1 = exp2f(sacc[mi][ni][1] * qscale);
                const float p2 = exp2f(sacc[mi][ni][2] * qscale);
                const float p3 = exp2f(sacc[mi][ni][3] * qscale);
                lsum[mi][0] += p0;
                lsum[mi][1] += p1;
                lsum[mi][2] += p2;
                lsum[mi][3] += p3;
                const unsigned pw = pk_fp8x4(p0, p1, p2, p3);
                const int chunk = wcg * 2 + ni;       // 16B chunk = col>>4
                #pragma unroll
                for (int r = 0; r < 4; r++) {
                    const int prow = wm + mi * 16 + quad * 4 + r;
                    Pl[prow * 128 + ((chunk ^ (prow & 7)) << 4) + fr] =
                        (uint8_t)(pw >> (8 * r));
                }
            }
        }
        __syncthreads();   // B: P(t) visible; all sK reads done
        // ---- prefetch stage(t+1) (drains at next A-barrier, under PV) ----
        if (tt < 15) STAGE(t + 1);
        // ---- O += P @ V_tile (64 rows x 64 ch per wave, K=128) ----
        __builtin_amdgcn_s_setprio(1);
        #pragma unroll
        for (int mi = 0; mi < 4; mi++) {
            const int prow = mi * 16 + fr;
            const uint4 lo = *(const uint4*)&Pl[prow * 128 + (((2 * quad) ^ sw) << 4)];
            const uint4 hi = *(const uint4*)&Pl[prow * 128 + (((2 * quad + 1) ^ sw) << 4)];
            const v8i aP = (v8i){(int)lo.x, (int)lo.y, (int)lo.z, (int)lo.w,
                                 (int)hi.x, (int)hi.y, (int)hi.z, (int)hi.w};
            #pragma unroll
            for (int ni = 0; ni < 4; ni++)
                oacc[mi][ni] = __builtin_amdgcn_mfma_scale_f32_16x16x128_f8f6f4(
                    aP, bV[ni], oacc[mi][ni], 0, 0, 0, 0x7f7f7f7fu, 0,
                    0x7f7f7f7fu);
        }
        __builtin_amdgcn_s_setprio(0);
    }
#undef STAGE

    // ---- l reduction: over fr (16 lanes), then across the 4 col-groups ----
    #pragma unroll
    for (int mi = 0; mi < 2; mi++)
        #pragma unroll
        for (int r = 0; r < 4; r++) {
            #pragma unroll
            for (int off = 1; off < 16; off <<= 1)
                lsum[mi][r] += __shfl_xor(lsum[mi][r], off);
        }
    if ((lane & 15) == 0) {
        #pragma unroll
        for (int mi = 0; mi < 2; mi++)
            #pragma unroll
            for (int r = 0; r < 4; r++)
                lpart[wave][mi * 16 + quad * 4 + r] = lsum[mi][r];
    }
    __syncthreads();
    if (tid < 64) {
        const int wr_ = tid >> 5, rl = tid & 31;
        const float L = lpart[wr_ * 4 + 0][rl] + lpart[wr_ * 4 + 1][rl] +
                        lpart[wr_ * 4 + 2][rl] + lpart[wr_ * 4 + 3][rl];
        lp[(long)half * 16384 + qbase + tid] = L;
    }
    // ---- unnormalized f32 partial store (no LDS bounce needed) ----
    {
        float* ob = op + ((long)half * 16384 + qbase) * 512;
        #pragma unroll
        for (int mi = 0; mi < 4; mi++)
            #pragma unroll
            for (int ni = 0; ni < 4; ni++) {
                const int col = wave * 64 + ni * 16 + fr;
                #pragma unroll
                for (int r = 0; r < 4; r++) {
                    const int row = mi * 16 + quad * 4 + r;
                    ob[(long)row * 512 + col] = oacc[mi][ni][r];
                }
            }
    }
}

// ---------------------------------------------------------------------------
// Combine split-KV partials: ao = bf16((O0+O1) * rcp(l0+l1)).  Memory-bound.
// ---------------------------------------------------------------------------
__global__ __launch_bounds__(256) void attn_combine(const float* __restrict__ op,
                                                    const float* __restrict__ lp,
                                                    uint16_t* __restrict__ ao) {
    const long i4 = (long)blockIdx.x * 256 + threadIdx.x;   // 0..2097151
    const long row = (i4 * 4) >> 9;
    const float4 a = ((const float4*)op)[i4];
    const float4 b = ((const float4*)(op + 16384L * 512))[i4];
    const float linv = __builtin_amdgcn_rcpf(lp[row] + lp[16384 + row]);
    union { ushort4 u; uint16_t s[4]; } o;
    o.s[0] = f2b((a.x + b.x) * linv);
    o.s[1] = f2b((a.y + b.y) * linv);
    o.s[2] = f2b((a.z + b.z) * linv);
    o.s[3] = f2b((a.w + b.w) * linv);
    ((ushort4*)ao)[i4] = o.u;
}

// ---------------------------------------------------------------------------
// Projection GEMM (bf16 MFMA): out = ao @ wp^T + bp + x   (f32 out)
// ---------------------------------------------------------------------------
__global__ __launch_bounds__(256) void gemm_proj(const uint16_t* __restrict__ A,
                                                 const uint16_t* __restrict__ B,
                                                 float* __restrict__ Cout,
                                                 const float* __restrict__ bias,
                                                 const float* __restrict__ resid) {
    __shared__ __align__(16) uint16_t smem[128 * 136];
    uint16_t* sA = smem;
    uint16_t* sB = smem + 8192;
    const int N = 512;

    const int tid = threadIdx.x;
    const long m0 = (long)blockIdx.y * 128;
    const long n0 = (long)blockIdx.x * 128;

    const int lane = tid & 63;
    const int wave = tid >> 6;
    const int wm = (wave & 1) * 64;
    const int wn = (wave >> 1) * 64;
    const int fr = lane & 15;
    const int fh = lane >> 4;
    const int sw = fr & 7;

    floatx4 acc[4][4];
    #pragma unroll
    for (int i = 0; i < 4; i++)
        #pragma unroll
        for (int j = 0; j < 4; j++) acc[i][j] = (floatx4){0.f, 0.f, 0.f, 0.f};

    for (int kt = 0; kt < 512; kt += 64) {
        __syncthreads();
        #pragma unroll
        for (int i = 0; i < 4; i++) {
            const int c = i * 256 + tid;
            const int row = c >> 3;
            const int gj = (c & 7) ^ (row & 7);
            lds_copy16(&sA[c * 8], A + (m0 + row) * 512L + kt + gj * 8);
            lds_copy16(&sB[c * 8], B + (n0 + row) * 512L + kt + gj * 8);
        }
        __syncthreads();
        #pragma unroll
        for (int kk = 0; kk < 64; kk += 32) {
            const int jx = ((fh + (kk >> 3)) ^ sw) * 8;
            bf16x8 av[4], bv[4];
            #pragma unroll
            for (int mi = 0; mi < 4; mi++)
                av[mi] = *(const bf16x8*)&sA[(wm + mi * 16 + fr) * 64 + jx];
            #pragma unroll
            for (int ni = 0; ni < 4; ni++)
                bv[ni] = *(const bf16x8*)&sB[(wn + ni * 16 + fr) * 64 + jx];
            #pragma unroll
            for (int mi = 0; mi < 4; mi++)
                #pragma unroll
                for (int ni = 0; ni < 4; ni++)
                    acc[mi][ni] = __builtin_amdgcn_mfma_f32_16x16x32_bf16(
                        av[mi], bv[ni], acc[mi][ni], 0, 0, 0);
        }
    }

    const int quad = lane >> 4;
    #pragma unroll
    for (int ni = 0; ni < 4; ni++) {
        const long col = n0 + wn + ni * 16 + fr;
        const float bv_ = bias[col];
        #pragma unroll
        for (int mi = 0; mi < 4; mi++) {
            #pragma unroll
            for (int r = 0; r < 4; r++) {
                const long row = m0 + wm + mi * 16 + quad * 4 + r;
                Cout[row * N + col] = acc[mi][ni][r] + bv_ + resid[row * N + col];
            }
        }
    }
}

// ---------------------------------------------------------------------------
extern "C" void kernel_launch(void* const* d_in, const int* in_sizes, int n_in,
                              void* d_out, int out_size, void* d_ws, size_t ws_size,
                              hipStream_t stream) {
    const float* x  = (const float*)d_in[0];
    const float* gg = (const float*)d_in[1];
    const float* gb = (const float*)d_in[2];
    const float* wq = (const float*)d_in[3];
    const float* bq = (const float*)d_in[4];
    const float* wk = (const float*)d_in[5];
    const float* bk = (const float*)d_in[6];
    const float* wv = (const float*)d_in[7];
    const float* bv = (const float*)d_in[8];
    const float* wp = (const float*)d_in[9];
    const float* bp = (const float*)d_in[10];
    float* out = (float*)d_out;

    char* ws = (char*)d_ws;
    size_t off = 0;
    auto alloc = [&](size_t bytes) {
        char* p = ws + off;
        off += (bytes + 255) & ~(size_t)255;
        return p;
    };
    float*    stats = (float*)alloc(128 * 2 * sizeof(float));
    uint16_t* h     = (uint16_t*)alloc(16384L * 512 * 2);
    uint16_t* wT    = (uint16_t*)alloc(4L * 512 * 512 * 2);
    uint8_t*  q8    = (uint8_t*)alloc(16384L * 512);
    uint8_t*  k8    = (uint8_t*)alloc(16384L * 512);
    uint8_t*  vt8   = (uint8_t*)alloc(16384L * 512);
    float*    op    = (float*)alloc(2L * 16384 * 512 * 4);
    float*    lp    = (float*)alloc(2L * 16384 * 4);
    uint16_t* ao    = (uint16_t*)alloc(16384L * 512 * 2);
    if (off > ws_size) return;  // workspace too small -> fail visibly

    gn_stats<<<128, 256, 0, stream>>>(x, stats);
    gn_apply<<<8192, 256, 0, stream>>>(x, stats, gg, gb, h);
    wcast_transpose<<<dim3(8, 8, 4), 256, 0, stream>>>(wq, wk, wv, wp, wT);

    // q / k / v^T (fp8) in one dispatch
    qkv_gemm<<<dim3(12, 128), 256, 0, stream>>>(h, wT, bq, bk, bv, q8, k8, vt8);
    // split-KV fused softmax(QK^T)V -> f32 partials
    flash_attn<<<dim3(512), dim3(512), 0, stream>>>(q8, k8, vt8, op, lp);
    // combine halves + normalize -> bf16 ao
    attn_combine<<<8192, 256, 0, stream>>>(op, lp, ao);
    // out = x + ao @ wp + bp
    gemm_proj<<<dim3(4, 128), 256, 0, stream>>>(ao, wT + 3 * 262144, out, bp, x);
}

// Round 10
// 331.449 us; speedup vs baseline: 2.2525x; 2.2525x over previous
//
#include <hip/hip_runtime.h>
#include <cstdint>

// ---------------------------------------------------------------------------
// VAE attention block: GN -> QKV 1x1 conv -> softmax(QK^T) V -> proj + x
// B=4, H=W=64 (N=4096 pixels/batch), C=512, GROUPS=32
// R12: revert to the measured-best R6 two-pass structure (313 us; the fused
// flash line is walled at 143 us by a register/LDS tradeoff: 2 blocks/CU
// needs <=128 regs => QBLK<=32 => 2x K-staging; v5's QBLK=64 attempt spilled
// oacc to scratch, 2 GB of spill traffic). Single change vs R6:
//   T1 XCD-chunked block swizzle on all four MFMA GEMMs (1D grids, %8==0):
//   same-batch blocks colocate per XCD so q/k (scores) and vt (PV) panels
//   (2-3 MB/batch) become L2-resident instead of ~32x L3 re-fetch.
// ---------------------------------------------------------------------------

typedef __bf16 bf16_t;
typedef bf16_t bf16x8 __attribute__((ext_vector_type(8)));
typedef float floatx4 __attribute__((ext_vector_type(4)));
typedef int v8i __attribute__((ext_vector_type(8)));

__device__ __forceinline__ uint16_t f2b(float f) {
    uint32_t u = __builtin_bit_cast(uint32_t, f);
    u += 0x7fffu + ((u >> 16) & 1u);
    return (uint16_t)(u >> 16);
}
__device__ __forceinline__ float b2f(uint16_t h) {
    uint32_t u = ((uint32_t)h) << 16;
    return __builtin_bit_cast(float, u);
}
// pack 4 floats -> 4 fp8 e4m3 bytes
__device__ __forceinline__ unsigned pk_fp8x4(float a, float b, float c, float d) {
    int w = __builtin_amdgcn_cvt_pk_fp8_f32(a, b, 0, false);
    w = __builtin_amdgcn_cvt_pk_fp8_f32(c, d, w, true);
    return (unsigned)w;
}

__device__ __forceinline__ void lds_copy16(void* lds, const void* glob) {
    __builtin_amdgcn_global_load_lds(
        (__attribute__((address_space(1))) void*)(void*)glob,
        (__attribute__((address_space(3))) void*)lds,
        16, 0, 0);
}

// ---------------------------------------------------------------------------
// GroupNorm stats: one block per (batch, group). Also zeroes the row-sum
// buffer (harness re-poisons workspace before every launch).
// ---------------------------------------------------------------------------
__global__ __launch_bounds__(256) void gn_stats(const float* __restrict__ x,
                                                float* __restrict__ stats,
                                                float* __restrict__ lrow) {
    const int bg = blockIdx.x;            // 0..127
    const int tid = threadIdx.x;
    if (tid < 128) lrow[bg * 128 + tid] = 0.f;   // 128*128 = 16384 rows
    const int b = bg >> 5, g = bg & 31;
    const float* base = x + (long)b * (4096L * 512) + g * 16;
    float s = 0.f, sq = 0.f;
    #pragma unroll 8
    for (int i = 0; i < 64; i++) {
        int idx4 = tid + i * 256;          // float4 index within group
        int pixel = idx4 >> 2, c4 = idx4 & 3;
        const float4 v = *(const float4*)(base + (long)pixel * 512 + c4 * 4);
        s += v.x + v.y + v.z + v.w;
        sq += v.x * v.x + v.y * v.y + v.z * v.z + v.w * v.w;
    }
    #pragma unroll
    for (int off = 32; off > 0; off >>= 1) {
        s += __shfl_down(s, off);
        sq += __shfl_down(sq, off);
    }
    __shared__ float rs[4], rq[4];
    const int lane = tid & 63, w = tid >> 6;
    if (lane == 0) { rs[w] = s; rq[w] = sq; }
    __syncthreads();
    if (tid == 0) {
        float S = rs[0] + rs[1] + rs[2] + rs[3];
        float Q = rq[0] + rq[1] + rq[2] + rq[3];
        float mean = S * (1.f / 65536.f);
        float var = Q * (1.f / 65536.f) - mean * mean;
        stats[bg * 2 + 0] = mean;
        stats[bg * 2 + 1] = rsqrtf(var + 1e-5f);
    }
}

// ---------------------------------------------------------------------------
// GroupNorm apply: h_bf16 = (x-mean)*rstd*gamma + beta.  4 elems/thread.
// ---------------------------------------------------------------------------
__global__ __launch_bounds__(256) void gn_apply(const float* __restrict__ x,
                                                const float* __restrict__ stats,
                                                const float* __restrict__ gamma,
                                                const float* __restrict__ beta,
                                                uint16_t* __restrict__ h) {
    const long idx4 = (long)blockIdx.x * 256 + threadIdx.x;   // 0..2097151
    const long e0 = idx4 * 4;
    const int c = (int)(e0 & 511);
    const int b = (int)(e0 >> 21);                            // 4096*512 = 2^21
    const float2 st = ((const float2*)stats)[b * 32 + (c >> 4)];
    const float4 v = ((const float4*)x)[idx4];
    const float4 gm = ((const float4*)gamma)[c >> 2];
    const float4 bt = ((const float4*)beta)[c >> 2];
    union { ushort4 u; uint16_t s[4]; } o;
    o.s[0] = f2b((v.x - st.x) * st.y * gm.x + bt.x);
    o.s[1] = f2b((v.y - st.x) * st.y * gm.y + bt.y);
    o.s[2] = f2b((v.z - st.x) * st.y * gm.z + bt.z);
    o.s[3] = f2b((v.w - st.x) * st.y * gm.w + bt.w);
    ((ushort4*)h)[idx4] = o.u;
}

// ---------------------------------------------------------------------------
// Cast+transpose weights: wT[d][c] = bf16(w[c][d]), 512x512, 64x64 LDS tiles.
// ---------------------------------------------------------------------------
__global__ __launch_bounds__(256) void wcast_transpose(const float* __restrict__ w0,
                                                       const float* __restrict__ w1,
                                                       const float* __restrict__ w2,
                                                       const float* __restrict__ w3,
                                                       uint16_t* __restrict__ out) {
    const float* ws[4] = {w0, w1, w2, w3};
    const float* w = ws[blockIdx.z];
    uint16_t* o = out + (long)blockIdx.z * 512 * 512;
    __shared__ uint16_t t[64][65];
    const int nb = blockIdx.x * 64, kb = blockIdx.y * 64;
    const int lc = threadIdx.x & 63, lg = threadIdx.x >> 6;
    #pragma unroll
    for (int i = 0; i < 16; i++) {
        int r = lg * 16 + i;
        t[lc][r] = f2b(w[(long)(kb + r) * 512 + nb + lc]);   // t[n_loc][k_loc]
    }
    __syncthreads();
    #pragma unroll
    for (int i = 0; i < 16; i++) {
        int r = lg * 16 + i;
        o[(long)(nb + r) * 512 + kb + lc] = t[r][lc];        // wT[n][k]
    }
}

// ---------------------------------------------------------------------------
// Fused QKV GEMM (bf16 MFMA): [16384,512] x [1536,512]^T.  1D grid 1536,
// XCD-chunked (192 consecutive tiles per XCD -> A panels + wT L2-resident).
// Outputs fp8 e4m3: cols 0-511 -> q, 512-1023 -> k, 1024-1535 -> v stored
// TRANSPOSED (vt[b][ch][pix]).  No scale on q (moved to scores epilogue).
// ---------------------------------------------------------------------------
__global__ __launch_bounds__(256) void qkv_gemm(const uint16_t* __restrict__ h,
                                                const uint16_t* __restrict__ wT,
                                                const float* __restrict__ bq,
                                                const float* __restrict__ bk,
                                                const float* __restrict__ bv,
                                                uint8_t* __restrict__ q,
                                                uint8_t* __restrict__ k,
                                                uint8_t* __restrict__ vt) {
    __shared__ __align__(16) uint16_t smem[128 * 136];
    uint16_t* sA = smem;
    uint16_t* sB = smem + 8192;

    const int tid = threadIdx.x;
    // XCD swizzle: 1536 blocks, 192/XCD; lb consecutive share the m-panel.
    const int lb = (blockIdx.x & 7) * (1536 / 8) + (blockIdx.x >> 3);
    const long m0 = (long)(lb / 12) * 128;
    const int n0 = (lb % 12) * 128;

    const int lane = tid & 63;
    const int wave = tid >> 6;
    const int wm = (wave & 1) * 64;
    const int wn = (wave >> 1) * 64;
    const int fr = lane & 15;
    const int fh = lane >> 4;
    const int sw = fr & 7;

    floatx4 acc[4][4];
    #pragma unroll
    for (int i = 0; i < 4; i++)
        #pragma unroll
        for (int j = 0; j < 4; j++) acc[i][j] = (floatx4){0.f, 0.f, 0.f, 0.f};

    for (int kt = 0; kt < 512; kt += 64) {
        __syncthreads();
        #pragma unroll
        for (int i = 0; i < 4; i++) {
            const int c = i * 256 + tid;
            const int row = c >> 3;
            const int gj = (c & 7) ^ (row & 7);
            lds_copy16(&sA[c * 8], h + (m0 + row) * 512L + kt + gj * 8);
            lds_copy16(&sB[c * 8], wT + (n0 + row) * 512L + kt + gj * 8);
        }
        __syncthreads();
        #pragma unroll
        for (int kk = 0; kk < 64; kk += 32) {
            const int jx = ((fh + (kk >> 3)) ^ sw) * 8;
            bf16x8 av[4], bv_[4];
            #pragma unroll
            for (int mi = 0; mi < 4; mi++)
                av[mi] = *(const bf16x8*)&sA[(wm + mi * 16 + fr) * 64 + jx];
            #pragma unroll
            for (int ni = 0; ni < 4; ni++)
                bv_[ni] = *(const bf16x8*)&sB[(wn + ni * 16 + fr) * 64 + jx];
            #pragma unroll
            for (int mi = 0; mi < 4; mi++)
                #pragma unroll
                for (int ni = 0; ni < 4; ni++)
                    acc[mi][ni] = __builtin_amdgcn_mfma_f32_16x16x32_bf16(
                        av[mi], bv_[ni], acc[mi][ni], 0, 0, 0);
        }
    }

    const int quad = lane >> 4;
    const int w = n0 >> 9;          // 0=q, 1=k, 2=v(T)
    const int nc = n0 & 511;
    const float* bias = (w == 0) ? bq : (w == 1) ? bk : bv;
    __syncthreads();
    if (w < 2) {
        // repack bf16 rows, then fp8-convert during the coalesced store
        #pragma unroll
        for (int ni = 0; ni < 4; ni++) {
            const int col_l = wn + ni * 16 + fr;
            const float bb = bias[nc + col_l];
            #pragma unroll
            for (int mi = 0; mi < 4; mi++) {
                #pragma unroll
                for (int r = 0; r < 4; r++) {
                    const int row_l = wm + mi * 16 + quad * 4 + r;
                    smem[row_l * 136 + col_l] = f2b(acc[mi][ni][r] + bb);
                }
            }
        }
        __syncthreads();
        uint8_t* out = (w == 0) ? q : k;
        #pragma unroll
        for (int it = 0; it < 8; it++) {
            const int row_l = it * 16 + (tid >> 4);
            const int c0 = (tid & 15) * 8;
            const uint4 d = *(const uint4*)&smem[row_l * 136 + c0];
            const uint16_t* e = (const uint16_t*)&d;
            uint2 o;
            o.x = pk_fp8x4(b2f(e[0]), b2f(e[1]), b2f(e[2]), b2f(e[3]));
            o.y = pk_fp8x4(b2f(e[4]), b2f(e[5]), b2f(e[6]), b2f(e[7]));
            *(uint2*)&out[(m0 + row_l) * 512 + nc + c0] = o;
        }
    } else {
        // transposed fp8 repack: s8[ch][pix], byte stride 144 (16B-aligned)
        uint8_t* s8 = (uint8_t*)smem;
        #pragma unroll
        for (int ni = 0; ni < 4; ni++) {
            const int ch_l = wn + ni * 16 + fr;
            const float bb = bias[nc + ch_l];
            #pragma unroll
            for (int mi = 0; mi < 4; mi++) {
                const int pix0 = wm + mi * 16 + quad * 4;
                *(unsigned*)&s8[ch_l * 144 + pix0] =
                    pk_fp8x4(acc[mi][ni][0] + bb, acc[mi][ni][1] + bb,
                             acc[mi][ni][2] + bb, acc[mi][ni][3] + bb);
            }
        }
        __syncthreads();
        const long b = m0 >> 12;
        const int pixb = (int)(m0 & 4095);
        uint8_t* vtb = vt + b * (512L * 4096);
        #pragma unroll
        for (int it = 0; it < 4; it++) {
            const int ch_l = it * 32 + (tid >> 3);
            const int p0 = (tid & 7) * 16;
            *(uint4*)&vtb[(long)(nc + ch_l) * 4096 + pixb + p0] =
                *(const uint4*)&s8[ch_l * 144 + p0];
        }
    }
}

// ---------------------------------------------------------------------------
// fp8 MFMA GEMM (MX-scaled, unit scales): C = A . B^T, A/B fp8 e4m3 with K
// contiguous (byte strides). 128x128 tile, BK=128 bytes, 4 waves x 4x4 of
// 16x16x128 mfma_scale. XOR-swizzled 16B-chunk LDS staging. 1D grid,
// XCD-chunked so each XCD owns consecutive tiles of one batch (A/B panels
// L2-resident: scores q+k = 4 MB/batch, PV vt = 2 MB/batch).
// MODE 3 (scores): p = exp2(acc*scale) -> bf16 LDS repack -> fp8 out + fp32
//                  row-sum atomics into lrow.
// MODE 4 (PV):     acc / lrow[row] -> bf16 out.
// ---------------------------------------------------------------------------
template <int MODE>
__global__ __launch_bounds__(256) void gemm_f8(const uint8_t* __restrict__ A,
                                               const uint8_t* __restrict__ B,
                                               void* __restrict__ Cout,
                                               float* __restrict__ lrow,
                                               float scale, int M, int N, int K,
                                               long aStride, long bStride, long cStride) {
    __shared__ __align__(16) uint16_t smem[128 * 136];   // 34816 B; staging uses 32768
    __shared__ float lbuf[128];
    uint8_t* sA = (uint8_t*)smem;
    uint8_t* sB = (uint8_t*)smem + 16384;

    const int tid = threadIdx.x;
    // XCD-chunked decode: grid is 1D, divisible by 8.
    const int nbx = N >> 7, nby = M >> 7;
    const int pb = nbx * nby;                       // blocks per batch
    const int lb = (blockIdx.x & 7) * ((int)gridDim.x >> 3) + (blockIdx.x >> 3);
    const int bz = lb / pb;
    const int rem = lb - bz * pb;
    const long m0 = (long)(rem / nbx) * 128;
    const long n0 = (long)(rem % nbx) * 128;
    const uint8_t* Ab = A + (long)bz * aStride;
    const uint8_t* Bb = B + (long)bz * bStride;

    const int lane = tid & 63;
    const int wave = tid >> 6;
    const int wm = (wave & 1) * 64;
    const int wn = (wave >> 1) * 64;
    const int fr = lane & 15;
    const int quad = lane >> 4;
    const int sw = fr & 7;

    floatx4 acc[4][4];
    #pragma unroll
    for (int i = 0; i < 4; i++)
        #pragma unroll
        for (int j = 0; j < 4; j++) acc[i][j] = (floatx4){0.f, 0.f, 0.f, 0.f};

    const int p0c = (2 * quad) ^ sw;       // swizzled 16B-chunk indices
    const int p1c = (2 * quad + 1) ^ sw;

    for (int kt = 0; kt < K; kt += 128) {
        __syncthreads();
        #pragma unroll
        for (int i = 0; i < 4; i++) {
            const int c = i * 256 + tid;           // 1024 chunks per matrix
            const int row = c >> 3;
            const int gj = (c & 7) ^ (row & 7);
            lds_copy16(&sA[c * 16], Ab + (m0 + row) * (long)K + kt + gj * 16);
            lds_copy16(&sB[c * 16], Bb + (n0 + row) * (long)K + kt + gj * 16);
        }
        __syncthreads();
        v8i af[4], bf[4];
        #pragma unroll
        for (int mi = 0; mi < 4; mi++) {
            const int row = wm + mi * 16 + fr;
            const uint4 lo = *(const uint4*)&sA[row * 128 + p0c * 16];
            const uint4 hi = *(const uint4*)&sA[row * 128 + p1c * 16];
            af[mi] = (v8i){(int)lo.x, (int)lo.y, (int)lo.z, (int)lo.w,
                           (int)hi.x, (int)hi.y, (int)hi.z, (int)hi.w};
        }
        #pragma unroll
        for (int ni = 0; ni < 4; ni++) {
            const int row = wn + ni * 16 + fr;
            const uint4 lo = *(const uint4*)&sB[row * 128 + p0c * 16];
            const uint4 hi = *(const uint4*)&sB[row * 128 + p1c * 16];
            bf[ni] = (v8i){(int)lo.x, (int)lo.y, (int)lo.z, (int)lo.w,
                           (int)hi.x, (int)hi.y, (int)hi.z, (int)hi.w};
        }
        #pragma unroll
        for (int mi = 0; mi < 4; mi++)
            #pragma unroll
            for (int ni = 0; ni < 4; ni++)
                acc[mi][ni] = __builtin_amdgcn_mfma_scale_f32_16x16x128_f8f6f4(
                    af[mi], bf[ni], acc[mi][ni], 0, 0,
                    0, 0x7f7f7f7fu, 0, 0x7f7f7f7fu);
    }

    __syncthreads();
    if (MODE == 4) {
        if (tid < 128) lbuf[tid] = lrow[(long)bz * M + m0 + tid];
        __syncthreads();
    }
    // repack to bf16 LDS tile (stride 136)
    #pragma unroll
    for (int ni = 0; ni < 4; ni++) {
        const int col_l = wn + ni * 16 + fr;
        #pragma unroll
        for (int mi = 0; mi < 4; mi++) {
            #pragma unroll
            for (int r = 0; r < 4; r++) {
                const int row_l = wm + mi * 16 + quad * 4 + r;
                float v = acc[mi][ni][r];
                if (MODE == 3) v = exp2f(v * scale);
                if (MODE == 4) v *= __builtin_amdgcn_rcpf(lbuf[row_l]);
                smem[row_l * 136 + col_l] = f2b(v);
            }
        }
    }
    __syncthreads();
    if (MODE == 3) {
        // fp8 out + row sums
        uint8_t* Cb = (uint8_t*)Cout + (long)bz * cStride;
        float* lb_ = lrow + (long)bz * M;
        #pragma unroll
        for (int it = 0; it < 8; it++) {
            const int row_l = it * 16 + (tid >> 4);
            const int c0 = (tid & 15) * 8;
            const uint4 d = *(const uint4*)&smem[row_l * 136 + c0];
            const uint16_t* e = (const uint16_t*)&d;
            float f[8];
            float ps = 0.f;
            #pragma unroll
            for (int j = 0; j < 8; j++) { f[j] = b2f(e[j]); ps += f[j]; }
            uint2 o;
            o.x = pk_fp8x4(f[0], f[1], f[2], f[3]);
            o.y = pk_fp8x4(f[4], f[5], f[6], f[7]);
            *(uint2*)&Cb[(m0 + row_l) * (long)N + n0 + c0] = o;
            #pragma unroll
            for (int off = 1; off < 16; off <<= 1) ps += __shfl_xor(ps, off);
            if ((tid & 15) == 0) atomicAdd(&lb_[m0 + row_l], ps);
        }
    } else {
        // bf16 out
        uint16_t* Cb = (uint16_t*)Cout + (long)bz * cStride;
        #pragma unroll
        for (int it = 0; it < 8; it++) {
            const int row_l = it * 16 + (tid >> 4);
            const int c0 = (tid & 15) * 8;
            *(uint4*)&Cb[(m0 + row_l) * (long)N + n0 + c0] =
                *(const uint4*)&smem[row_l * 136 + c0];
        }
    }
}

// ---------------------------------------------------------------------------
// Projection GEMM (bf16 MFMA): out = ao @ wp^T + bp + x   (f32 out)
// 1D grid 512, XCD-chunked (64 tiles/XCD share ao panels + wp in L2).
// ---------------------------------------------------------------------------
__global__ __launch_bounds__(256) void gemm_proj(const uint16_t* __restrict__ A,
                                                 const uint16_t* __restrict__ B,
                                                 float* __restrict__ Cout,
                                                 const float* __restrict__ bias,
                                                 const float* __restrict__ resid) {
    __shared__ __align__(16) uint16_t smem[128 * 136];
    uint16_t* sA = smem;
    uint16_t* sB = smem + 8192;
    const int N = 512;

    const int tid = threadIdx.x;
    const int lb = (blockIdx.x & 7) * (512 / 8) + (blockIdx.x >> 3);
    const long m0 = (long)(lb >> 2) * 128;
    const long n0 = (long)(lb & 3) * 128;

    const int lane = tid & 63;
    const int wave = tid >> 6;
    const int wm = (wave & 1) * 64;
    const int wn = (wave >> 1) * 64;
    const int fr = lane & 15;
    const int fh = lane >> 4;
    const int sw = fr & 7;

    floatx4 acc[4][4];
    #pragma unroll
    for (int i = 0; i < 4; i++)
        #pragma unroll
        for (int j = 0; j < 4; j++) acc[i][j] = (floatx4){0.f, 0.f, 0.f, 0.f};

    for (int kt = 0; kt < 512; kt += 64) {
        __syncthreads();
        #pragma unroll
        for (int i = 0; i < 4; i++) {
            const int c = i * 256 + tid;
            const int row = c >> 3;
            const int gj = (c & 7) ^ (row & 7);
            lds_copy16(&sA[c * 8], A + (m0 + row) * 512L + kt + gj * 8);
            lds_copy16(&sB[c * 8], B + (n0 + row) * 512L + kt + gj * 8);
        }
        __syncthreads();
        #pragma unroll
        for (int kk = 0; kk < 64; kk += 32) {
            const int jx = ((fh + (kk >> 3)) ^ sw) * 8;
            bf16x8 av[4], bv[4];
            #pragma unroll
            for (int mi = 0; mi < 4; mi++)
                av[mi] = *(const bf16x8*)&sA[(wm + mi * 16 + fr) * 64 + jx];
            #pragma unroll
            for (int ni = 0; ni < 4; ni++)
                bv[ni] = *(const bf16x8*)&sB[(wn + ni * 16 + fr) * 64 + jx];
            #pragma unroll
            for (int mi = 0; mi < 4; mi++)
                #pragma unroll
                for (int ni = 0; ni < 4; ni++)
                    acc[mi][ni] = __builtin_amdgcn_mfma_f32_16x16x32_bf16(
                        av[mi], bv[ni], acc[mi][ni], 0, 0, 0);
        }
    }

    const int quad = lane >> 4;
    #pragma unroll
    for (int ni = 0; ni < 4; ni++) {
        const long col = n0 + wn + ni * 16 + fr;
        const float bv_ = bias[col];
        #pragma unroll
        for (int mi = 0; mi < 4; mi++) {
            #pragma unroll
            for (int r = 0; r < 4; r++) {
                const long row = m0 + wm + mi * 16 + quad * 4 + r;
                Cout[row * N + col] = acc[mi][ni][r] + bv_ + resid[row * N + col];
            }
        }
    }
}

// ---------------------------------------------------------------------------
extern "C" void kernel_launch(void* const* d_in, const int* in_sizes, int n_in,
                              void* d_out, int out_size, void* d_ws, size_t ws_size,
                              hipStream_t stream) {
    const float* x  = (const float*)d_in[0];
    const float* gg = (const float*)d_in[1];
    const float* gb = (const float*)d_in[2];
    const float* wq = (const float*)d_in[3];
    const float* bq = (const float*)d_in[4];
    const float* wk = (const float*)d_in[5];
    const float* bk = (const float*)d_in[6];
    const float* wv = (const float*)d_in[7];
    const float* bv = (const float*)d_in[8];
    const float* wp = (const float*)d_in[9];
    const float* bp = (const float*)d_in[10];
    float* out = (float*)d_out;

    char* ws = (char*)d_ws;
    size_t off = 0;
    auto alloc = [&](size_t bytes) {
        char* p = ws + off;
        off += (bytes + 255) & ~(size_t)255;
        return p;
    };
    float*    stats = (float*)alloc(128 * 2 * sizeof(float));
    float*    lrow  = (float*)alloc(16384L * 4);
    uint16_t* h     = (uint16_t*)alloc(16384L * 512 * 2);
    uint16_t* wT    = (uint16_t*)alloc(4L * 512 * 512 * 2);
    uint8_t*  q8    = (uint8_t*)alloc(16384L * 512);
    uint8_t*  k8    = (uint8_t*)alloc(16384L * 512);
    uint8_t*  vt8   = (uint8_t*)alloc(16384L * 512);
    uint8_t*  sc8   = (uint8_t*)alloc(4L * 4096 * 4096);
    uint16_t* ao    = (uint16_t*)alloc(16384L * 512 * 2);
    if (off > ws_size) return;  // workspace too small -> fail visibly

    gn_stats<<<128, 256, 0, stream>>>(x, stats, lrow);
    gn_apply<<<8192, 256, 0, stream>>>(x, stats, gg, gb, h);
    wcast_transpose<<<dim3(8, 8, 4), 256, 0, stream>>>(wq, wk, wv, wp, wT);

    // q / k / v^T (fp8) in one dispatch (1D grid, XCD-chunked)
    qkv_gemm<<<1536, 256, 0, stream>>>(h, wT, bq, bk, bv, q8, k8, vt8);
    // p[b] = exp2(scale * q[b] @ k[b]^T) as fp8, row sums into lrow
    const float qscale = 0.06375871540654937f;   // log2(e)/sqrt(512)
    gemm_f8<3><<<4096, 256, 0, stream>>>(q8, k8, sc8, lrow, qscale,
                                         4096, 4096, 512,
                                         4096L * 512, 4096L * 512, 4096L * 4096);
    // ao[b] = (p[b] @ v[b]) / l    (fp8 x fp8 -> bf16)
    gemm_f8<4><<<512, 256, 0, stream>>>(sc8, vt8, ao, lrow, 1.f,
                                        4096, 512, 4096,
                                        4096L * 4096, 512L * 4096, 4096L * 512);
    // out = x + ao @ wp + bp
    gemm_proj<<<512, 256, 0, stream>>>(ao, wT + 3 * 262144, out, bp, x);
}

// Round 11
// 322.836 us; speedup vs baseline: 2.3126x; 1.0267x over previous
//
#include <hip/hip_runtime.h>
#include <cstdint>

// ---------------------------------------------------------------------------
// VAE attention block: GN -> QKV 1x1 conv -> softmax(QK^T) V -> proj + x
// B=4, H=W=64 (N=4096 pixels/batch), C=512, GROUPS=32
// R13: R12 post-mortem — XCD chunking on scores REGRESSED (fetch 37->13 MB
// proved L2 residency, but scores was never fetch-bound; m-major issue order
// added stalls). Revert all grids to R6 (313 us). Single change vs R6:
//   MODE-3 (scores) epilogue fully in-register: fp8 pack from f32, 4x4 byte
//   transpose via 2x shfl_xor + 2x v_perm per word, direct 4B stores
//   (4 lanes/row = 16B contiguous), row-sums from f32 p in registers.
//   Removes 64 f2b + 64 b2f + 128 conflicted LDS ops + 1 barrier per block.
// ---------------------------------------------------------------------------

typedef __bf16 bf16_t;
typedef bf16_t bf16x8 __attribute__((ext_vector_type(8)));
typedef float floatx4 __attribute__((ext_vector_type(4)));
typedef int v8i __attribute__((ext_vector_type(8)));

__device__ __forceinline__ uint16_t f2b(float f) {
    uint32_t u = __builtin_bit_cast(uint32_t, f);
    u += 0x7fffu + ((u >> 16) & 1u);
    return (uint16_t)(u >> 16);
}
__device__ __forceinline__ float b2f(uint16_t h) {
    uint32_t u = ((uint32_t)h) << 16;
    return __builtin_bit_cast(float, u);
}
// pack 4 floats -> 4 fp8 e4m3 bytes (byte 0 = first arg)
__device__ __forceinline__ unsigned pk_fp8x4(float a, float b, float c, float d) {
    int w = __builtin_amdgcn_cvt_pk_fp8_f32(a, b, 0, false);
    w = __builtin_amdgcn_cvt_pk_fp8_f32(c, d, w, true);
    return (unsigned)w;
}

__device__ __forceinline__ void lds_copy16(void* lds, const void* glob) {
    __builtin_amdgcn_global_load_lds(
        (__attribute__((address_space(1))) void*)(void*)glob,
        (__attribute__((address_space(3))) void*)lds,
        16, 0, 0);
}

// ---------------------------------------------------------------------------
// GroupNorm stats: one block per (batch, group). Also zeroes the row-sum
// buffer (harness re-poisons workspace before every launch).
// ---------------------------------------------------------------------------
__global__ __launch_bounds__(256) void gn_stats(const float* __restrict__ x,
                                                float* __restrict__ stats,
                                                float* __restrict__ lrow) {
    const int bg = blockIdx.x;            // 0..127
    const int tid = threadIdx.x;
    if (tid < 128) lrow[bg * 128 + tid] = 0.f;   // 128*128 = 16384 rows
    const int b = bg >> 5, g = bg & 31;
    const float* base = x + (long)b * (4096L * 512) + g * 16;
    float s = 0.f, sq = 0.f;
    #pragma unroll 8
    for (int i = 0; i < 64; i++) {
        int idx4 = tid + i * 256;          // float4 index within group
        int pixel = idx4 >> 2, c4 = idx4 & 3;
        const float4 v = *(const float4*)(base + (long)pixel * 512 + c4 * 4);
        s += v.x + v.y + v.z + v.w;
        sq += v.x * v.x + v.y * v.y + v.z * v.z + v.w * v.w;
    }
    #pragma unroll
    for (int off = 32; off > 0; off >>= 1) {
        s += __shfl_down(s, off);
        sq += __shfl_down(sq, off);
    }
    __shared__ float rs[4], rq[4];
    const int lane = tid & 63, w = tid >> 6;
    if (lane == 0) { rs[w] = s; rq[w] = sq; }
    __syncthreads();
    if (tid == 0) {
        float S = rs[0] + rs[1] + rs[2] + rs[3];
        float Q = rq[0] + rq[1] + rq[2] + rq[3];
        float mean = S * (1.f / 65536.f);
        float var = Q * (1.f / 65536.f) - mean * mean;
        stats[bg * 2 + 0] = mean;
        stats[bg * 2 + 1] = rsqrtf(var + 1e-5f);
    }
}

// ---------------------------------------------------------------------------
// GroupNorm apply: h_bf16 = (x-mean)*rstd*gamma + beta.  4 elems/thread.
// ---------------------------------------------------------------------------
__global__ __launch_bounds__(256) void gn_apply(const float* __restrict__ x,
                                                const float* __restrict__ stats,
                                                const float* __restrict__ gamma,
                                                const float* __restrict__ beta,
                                                uint16_t* __restrict__ h) {
    const long idx4 = (long)blockIdx.x * 256 + threadIdx.x;   // 0..2097151
    const long e0 = idx4 * 4;
    const int c = (int)(e0 & 511);
    const int b = (int)(e0 >> 21);                            // 4096*512 = 2^21
    const float2 st = ((const float2*)stats)[b * 32 + (c >> 4)];
    const float4 v = ((const float4*)x)[idx4];
    const float4 gm = ((const float4*)gamma)[c >> 2];
    const float4 bt = ((const float4*)beta)[c >> 2];
    union { ushort4 u; uint16_t s[4]; } o;
    o.s[0] = f2b((v.x - st.x) * st.y * gm.x + bt.x);
    o.s[1] = f2b((v.y - st.x) * st.y * gm.y + bt.y);
    o.s[2] = f2b((v.z - st.x) * st.y * gm.z + bt.z);
    o.s[3] = f2b((v.w - st.x) * st.y * gm.w + bt.w);
    ((ushort4*)h)[idx4] = o.u;
}

// ---------------------------------------------------------------------------
// Cast+transpose weights: wT[d][c] = bf16(w[c][d]), 512x512, 64x64 LDS tiles.
// ---------------------------------------------------------------------------
__global__ __launch_bounds__(256) void wcast_transpose(const float* __restrict__ w0,
                                                       const float* __restrict__ w1,
                                                       const float* __restrict__ w2,
                                                       const float* __restrict__ w3,
                                                       uint16_t* __restrict__ out) {
    const float* ws[4] = {w0, w1, w2, w3};
    const float* w = ws[blockIdx.z];
    uint16_t* o = out + (long)blockIdx.z * 512 * 512;
    __shared__ uint16_t t[64][65];
    const int nb = blockIdx.x * 64, kb = blockIdx.y * 64;
    const int lc = threadIdx.x & 63, lg = threadIdx.x >> 6;
    #pragma unroll
    for (int i = 0; i < 16; i++) {
        int r = lg * 16 + i;
        t[lc][r] = f2b(w[(long)(kb + r) * 512 + nb + lc]);   // t[n_loc][k_loc]
    }
    __syncthreads();
    #pragma unroll
    for (int i = 0; i < 16; i++) {
        int r = lg * 16 + i;
        o[(long)(nb + r) * 512 + kb + lc] = t[r][lc];        // wT[n][k]
    }
}

// ---------------------------------------------------------------------------
// Fused QKV GEMM (bf16 MFMA): [16384,512] x [1536,512]^T.  Grid (12, 128).
// Outputs fp8 e4m3: cols 0-511 -> q, 512-1023 -> k, 1024-1535 -> v stored
// TRANSPOSED (vt[b][ch][pix]).  No scale on q (moved to scores epilogue).
// ---------------------------------------------------------------------------
__global__ __launch_bounds__(256) void qkv_gemm(const uint16_t* __restrict__ h,
                                                const uint16_t* __restrict__ wT,
                                                const float* __restrict__ bq,
                                                const float* __restrict__ bk,
                                                const float* __restrict__ bv,
                                                uint8_t* __restrict__ q,
                                                uint8_t* __restrict__ k,
                                                uint8_t* __restrict__ vt) {
    __shared__ __align__(16) uint16_t smem[128 * 136];
    uint16_t* sA = smem;
    uint16_t* sB = smem + 8192;

    const int tid = threadIdx.x;
    const long m0 = (long)blockIdx.y * 128;
    const int n0 = blockIdx.x * 128;

    const int lane = tid & 63;
    const int wave = tid >> 6;
    const int wm = (wave & 1) * 64;
    const int wn = (wave >> 1) * 64;
    const int fr = lane & 15;
    const int fh = lane >> 4;
    const int sw = fr & 7;

    floatx4 acc[4][4];
    #pragma unroll
    for (int i = 0; i < 4; i++)
        #pragma unroll
        for (int j = 0; j < 4; j++) acc[i][j] = (floatx4){0.f, 0.f, 0.f, 0.f};

    for (int kt = 0; kt < 512; kt += 64) {
        __syncthreads();
        #pragma unroll
        for (int i = 0; i < 4; i++) {
            const int c = i * 256 + tid;
            const int row = c >> 3;
            const int gj = (c & 7) ^ (row & 7);
            lds_copy16(&sA[c * 8], h + (m0 + row) * 512L + kt + gj * 8);
            lds_copy16(&sB[c * 8], wT + (n0 + row) * 512L + kt + gj * 8);
        }
        __syncthreads();
        #pragma unroll
        for (int kk = 0; kk < 64; kk += 32) {
            const int jx = ((fh + (kk >> 3)) ^ sw) * 8;
            bf16x8 av[4], bv_[4];
            #pragma unroll
            for (int mi = 0; mi < 4; mi++)
                av[mi] = *(const bf16x8*)&sA[(wm + mi * 16 + fr) * 64 + jx];
            #pragma unroll
            for (int ni = 0; ni < 4; ni++)
                bv_[ni] = *(const bf16x8*)&sB[(wn + ni * 16 + fr) * 64 + jx];
            #pragma unroll
            for (int mi = 0; mi < 4; mi++)
                #pragma unroll
                for (int ni = 0; ni < 4; ni++)
                    acc[mi][ni] = __builtin_amdgcn_mfma_f32_16x16x32_bf16(
                        av[mi], bv_[ni], acc[mi][ni], 0, 0, 0);
        }
    }

    const int quad = lane >> 4;
    const int w = n0 >> 9;          // 0=q, 1=k, 2=v(T)
    const int nc = n0 & 511;
    const float* bias = (w == 0) ? bq : (w == 1) ? bk : bv;
    __syncthreads();
    if (w < 2) {
        // repack bf16 rows, then fp8-convert during the coalesced store
        #pragma unroll
        for (int ni = 0; ni < 4; ni++) {
            const int col_l = wn + ni * 16 + fr;
            const float bb = bias[nc + col_l];
            #pragma unroll
            for (int mi = 0; mi < 4; mi++) {
                #pragma unroll
                for (int r = 0; r < 4; r++) {
                    const int row_l = wm + mi * 16 + quad * 4 + r;
                    smem[row_l * 136 + col_l] = f2b(acc[mi][ni][r] + bb);
                }
            }
        }
        __syncthreads();
        uint8_t* out = (w == 0) ? q : k;
        #pragma unroll
        for (int it = 0; it < 8; it++) {
            const int row_l = it * 16 + (tid >> 4);
            const int c0 = (tid & 15) * 8;
            const uint4 d = *(const uint4*)&smem[row_l * 136 + c0];
            const uint16_t* e = (const uint16_t*)&d;
            uint2 o;
            o.x = pk_fp8x4(b2f(e[0]), b2f(e[1]), b2f(e[2]), b2f(e[3]));
            o.y = pk_fp8x4(b2f(e[4]), b2f(e[5]), b2f(e[6]), b2f(e[7]));
            *(uint2*)&out[(m0 + row_l) * 512 + nc + c0] = o;
        }
    } else {
        // transposed fp8 repack: s8[ch][pix], byte stride 144 (16B-aligned)
        uint8_t* s8 = (uint8_t*)smem;
        #pragma unroll
        for (int ni = 0; ni < 4; ni++) {
            const int ch_l = wn + ni * 16 + fr;
            const float bb = bias[nc + ch_l];
            #pragma unroll
            for (int mi = 0; mi < 4; mi++) {
                const int pix0 = wm + mi * 16 + quad * 4;
                *(unsigned*)&s8[ch_l * 144 + pix0] =
                    pk_fp8x4(acc[mi][ni][0] + bb, acc[mi][ni][1] + bb,
                             acc[mi][ni][2] + bb, acc[mi][ni][3] + bb);
            }
        }
        __syncthreads();
        const long b = m0 >> 12;
        const int pixb = (int)(m0 & 4095);
        uint8_t* vtb = vt + b * (512L * 4096);
        #pragma unroll
        for (int it = 0; it < 4; it++) {
            const int ch_l = it * 32 + (tid >> 3);
            const int p0 = (tid & 7) * 16;
            *(uint4*)&vtb[(long)(nc + ch_l) * 4096 + pixb + p0] =
                *(const uint4*)&s8[ch_l * 144 + p0];
        }
    }
}

// ---------------------------------------------------------------------------
// fp8 MFMA GEMM (MX-scaled, unit scales): C = A . B^T, A/B fp8 e4m3 with K
// contiguous (byte strides). 128x128 tile, BK=128 bytes, 4 waves x 4x4 of
// 16x16x128 mfma_scale. XOR-swizzled 16B-chunk staging.
// MODE 3 (scores): p = exp2(acc*scale); IN-REGISTER epilogue: fp8 pack,
//   4x4 byte transpose (2 shfl_xor + 2 v_perm per word), direct 4B stores;
//   row sums from f32 p in registers + one atomic per row per wave.
// MODE 4 (PV):     acc / lrow[row] -> bf16 out (LDS repack, unchanged).
// ---------------------------------------------------------------------------
template <int MODE>
__global__ __launch_bounds__(256) void gemm_f8(const uint8_t* __restrict__ A,
                                               const uint8_t* __restrict__ B,
                                               void* __restrict__ Cout,
                                               float* __restrict__ lrow,
                                               float scale, int M, int N, int K,
                                               long aStride, long bStride, long cStride) {
    __shared__ __align__(16) uint16_t smem[128 * 136];   // 34816 B; staging uses 32768
    __shared__ float lbuf[128];
    uint8_t* sA = (uint8_t*)smem;
    uint8_t* sB = (uint8_t*)smem + 16384;

    const int tid = threadIdx.x;
    const int bz = blockIdx.z;
    const long m0 = (long)blockIdx.y * 128;
    const long n0 = (long)blockIdx.x * 128;
    const uint8_t* Ab = A + (long)bz * aStride;
    const uint8_t* Bb = B + (long)bz * bStride;

    const int lane = tid & 63;
    const int wave = tid >> 6;
    const int wm = (wave & 1) * 64;
    const int wn = (wave >> 1) * 64;
    const int fr = lane & 15;
    const int quad = lane >> 4;
    const int sw = fr & 7;

    floatx4 acc[4][4];
    #pragma unroll
    for (int i = 0; i < 4; i++)
        #pragma unroll
        for (int j = 0; j < 4; j++) acc[i][j] = (floatx4){0.f, 0.f, 0.f, 0.f};

    const int p0c = (2 * quad) ^ sw;       // swizzled 16B-chunk indices
    const int p1c = (2 * quad + 1) ^ sw;

    for (int kt = 0; kt < K; kt += 128) {
        __syncthreads();
        #pragma unroll
        for (int i = 0; i < 4; i++) {
            const int c = i * 256 + tid;           // 1024 chunks per matrix
            const int row = c >> 3;
            const int gj = (c & 7) ^ (row & 7);
            lds_copy16(&sA[c * 16], Ab + (m0 + row) * (long)K + kt + gj * 16);
            lds_copy16(&sB[c * 16], Bb + (n0 + row) * (long)K + kt + gj * 16);
        }
        __syncthreads();
        v8i af[4], bf[4];
        #pragma unroll
        for (int mi = 0; mi < 4; mi++) {
            const int row = wm + mi * 16 + fr;
            const uint4 lo = *(const uint4*)&sA[row * 128 + p0c * 16];
            const uint4 hi = *(const uint4*)&sA[row * 128 + p1c * 16];
            af[mi] = (v8i){(int)lo.x, (int)lo.y, (int)lo.z, (int)lo.w,
                           (int)hi.x, (int)hi.y, (int)hi.z, (int)hi.w};
        }
        #pragma unroll
        for (int ni = 0; ni < 4; ni++) {
            const int row = wn + ni * 16 + fr;
            const uint4 lo = *(const uint4*)&sB[row * 128 + p0c * 16];
            const uint4 hi = *(const uint4*)&sB[row * 128 + p1c * 16];
            bf[ni] = (v8i){(int)lo.x, (int)lo.y, (int)lo.z, (int)lo.w,
                           (int)hi.x, (int)hi.y, (int)hi.z, (int)hi.w};
        }
        #pragma unroll
        for (int mi = 0; mi < 4; mi++)
            #pragma unroll
            for (int ni = 0; ni < 4; ni++)
                acc[mi][ni] = __builtin_amdgcn_mfma_scale_f32_16x16x128_f8f6f4(
                    af[mi], bf[ni], acc[mi][ni], 0, 0,
                    0, 0x7f7f7f7fu, 0, 0x7f7f7f7fu);
    }

    if (MODE == 3) {
        // ---- fully in-register epilogue ----
        uint8_t* Cb = (uint8_t*)Cout + (long)bz * cStride;
        float* lb_ = lrow + (long)bz * M;
        // byte-transpose selectors (per-lane, depend on lane&1 / lane&2)
        const unsigned sel1 = (lane & 1) ? 0x07030501u : 0x02060004u;
        const unsigned sel2 = (lane & 2) ? 0x07060302u : 0x01000504u;
        float rsum[4][4];
        #pragma unroll
        for (int mi = 0; mi < 4; mi++)
            #pragma unroll
            for (int r = 0; r < 4; r++) rsum[mi][r] = 0.f;
        #pragma unroll
        for (int mi = 0; mi < 4; mi++) {
            #pragma unroll
            for (int ni = 0; ni < 4; ni++) {
                const float p0 = exp2f(acc[mi][ni][0] * scale);
                const float p1 = exp2f(acc[mi][ni][1] * scale);
                const float p2 = exp2f(acc[mi][ni][2] * scale);
                const float p3 = exp2f(acc[mi][ni][3] * scale);
                rsum[mi][0] += p0;
                rsum[mi][1] += p1;
                rsum[mi][2] += p2;
                rsum[mi][3] += p3;
                // word: bytes = rows r0..3 at col wn+ni*16+fr
                const unsigned w0 = pk_fp8x4(p0, p1, p2, p3);
                // 4x4 byte transpose across quartet {fr&~3 .. +3}
                const unsigned y = (unsigned)__shfl_xor((int)w0, 1);
                const unsigned s1 = __builtin_amdgcn_perm(w0, y, sel1);
                const unsigned z = (unsigned)__shfl_xor((int)s1, 2);
                const unsigned t = __builtin_amdgcn_perm(s1, z, sel2);
                // lane now holds row wm+mi*16+quad*4+(lane&3),
                // cols [wn+ni*16+(fr&12) .. +3]
                const long row = m0 + wm + mi * 16 + quad * 4 + (lane & 3);
                *(unsigned*)&Cb[row * (long)N + n0 + wn + ni * 16 + (fr & 12)] = t;
            }
        }
        // row sums: reduce over the 16 fr lanes, one atomic per row per wave
        #pragma unroll
        for (int mi = 0; mi < 4; mi++)
            #pragma unroll
            for (int r = 0; r < 4; r++) {
                float s = rsum[mi][r];
                #pragma unroll
                for (int off = 1; off < 16; off <<= 1) s += __shfl_xor(s, off);
                if (fr == 0)
                    atomicAdd(&lb_[m0 + wm + mi * 16 + quad * 4 + r], s);
            }
    } else {
        __syncthreads();
        if (tid < 128) lbuf[tid] = lrow[(long)bz * M + m0 + tid];
        __syncthreads();
        // repack to bf16 LDS tile (stride 136)
        #pragma unroll
        for (int ni = 0; ni < 4; ni++) {
            const int col_l = wn + ni * 16 + fr;
            #pragma unroll
            for (int mi = 0; mi < 4; mi++) {
                #pragma unroll
                for (int r = 0; r < 4; r++) {
                    const int row_l = wm + mi * 16 + quad * 4 + r;
                    float v = acc[mi][ni][r] * __builtin_amdgcn_rcpf(lbuf[row_l]);
                    smem[row_l * 136 + col_l] = f2b(v);
                }
            }
        }
        __syncthreads();
        uint16_t* Cb = (uint16_t*)Cout + (long)bz * cStride;
        #pragma unroll
        for (int it = 0; it < 8; it++) {
            const int row_l = it * 16 + (tid >> 4);
            const int c0 = (tid & 15) * 8;
            *(uint4*)&Cb[(m0 + row_l) * (long)N + n0 + c0] =
                *(const uint4*)&smem[row_l * 136 + c0];
        }
    }
}

// ---------------------------------------------------------------------------
// Projection GEMM (bf16 MFMA): out = ao @ wp^T + bp + x   (f32 out)
// ---------------------------------------------------------------------------
__global__ __launch_bounds__(256) void gemm_proj(const uint16_t* __restrict__ A,
                                                 const uint16_t* __restrict__ B,
                                                 float* __restrict__ Cout,
                                                 const float* __restrict__ bias,
                                                 const float* __restrict__ resid) {
    __shared__ __align__(16) uint16_t smem[128 * 136];
    uint16_t* sA = smem;
    uint16_t* sB = smem + 8192;
    const int N = 512;

    const int tid = threadIdx.x;
    const long m0 = (long)blockIdx.y * 128;
    const long n0 = (long)blockIdx.x * 128;

    const int lane = tid & 63;
    const int wave = tid >> 6;
    const int wm = (wave & 1) * 64;
    const int wn = (wave >> 1) * 64;
    const int fr = lane & 15;
    const int fh = lane >> 4;
    const int sw = fr & 7;

    floatx4 acc[4][4];
    #pragma unroll
    for (int i = 0; i < 4; i++)
        #pragma unroll
        for (int j = 0; j < 4; j++) acc[i][j] = (floatx4){0.f, 0.f, 0.f, 0.f};

    for (int kt = 0; kt < 512; kt += 64) {
        __syncthreads();
        #pragma unroll
        for (int i = 0; i < 4; i++) {
            const int c = i * 256 + tid;
            const int row = c >> 3;
            const int gj = (c & 7) ^ (row & 7);
            lds_copy16(&sA[c * 8], A + (m0 + row) * 512L + kt + gj * 8);
            lds_copy16(&sB[c * 8], B + (n0 + row) * 512L + kt + gj * 8);
        }
        __syncthreads();
        #pragma unroll
        for (int kk = 0; kk < 64; kk += 32) {
            const int jx = ((fh + (kk >> 3)) ^ sw) * 8;
            bf16x8 av[4], bv[4];
            #pragma unroll
            for (int mi = 0; mi < 4; mi++)
                av[mi] = *(const bf16x8*)&sA[(wm + mi * 16 + fr) * 64 + jx];
            #pragma unroll
            for (int ni = 0; ni < 4; ni++)
                bv[ni] = *(const bf16x8*)&sB[(wn + ni * 16 + fr) * 64 + jx];
            #pragma unroll
            for (int mi = 0; mi < 4; mi++)
                #pragma unroll
                for (int ni = 0; ni < 4; ni++)
                    acc[mi][ni] = __builtin_amdgcn_mfma_f32_16x16x32_bf16(
                        av[mi], bv[ni], acc[mi][ni], 0, 0, 0);
        }
    }

    const int quad = lane >> 4;
    #pragma unroll
    for (int ni = 0; ni < 4; ni++) {
        const long col = n0 + wn + ni * 16 + fr;
        const float bv_ = bias[col];
        #pragma unroll
        for (int mi = 0; mi < 4; mi++) {
            #pragma unroll
            for (int r = 0; r < 4; r++) {
                const long row = m0 + wm + mi * 16 + quad * 4 + r;
                Cout[row * N + col] = acc[mi][ni][r] + bv_ + resid[row * N + col];
            }
        }
    }
}

// ---------------------------------------------------------------------------
extern "C" void kernel_launch(void* const* d_in, const int* in_sizes, int n_in,
                              void* d_out, int out_size, void* d_ws, size_t ws_size,
                              hipStream_t stream) {
    const float* x  = (const float*)d_in[0];
    const float* gg = (const float*)d_in[1];
    const float* gb = (const float*)d_in[2];
    const float* wq = (const float*)d_in[3];
    const float* bq = (const float*)d_in[4];
    const float* wk = (const float*)d_in[5];
    const float* bk = (const float*)d_in[6];
    const float* wv = (const float*)d_in[7];
    const float* bv = (const float*)d_in[8];
    const float* wp = (const float*)d_in[9];
    const float* bp = (const float*)d_in[10];
    float* out = (float*)d_out;

    char* ws = (char*)d_ws;
    size_t off = 0;
    auto alloc = [&](size_t bytes) {
        char* p = ws + off;
        off += (bytes + 255) & ~(size_t)255;
        return p;
    };
    float*    stats = (float*)alloc(128 * 2 * sizeof(float));
    float*    lrow  = (float*)alloc(16384L * 4);
    uint16_t* h     = (uint16_t*)alloc(16384L * 512 * 2);
    uint16_t* wT    = (uint16_t*)alloc(4L * 512 * 512 * 2);
    uint8_t*  q8    = (uint8_t*)alloc(16384L * 512);
    uint8_t*  k8    = (uint8_t*)alloc(16384L * 512);
    uint8_t*  vt8   = (uint8_t*)alloc(16384L * 512);
    uint8_t*  sc8   = (uint8_t*)alloc(4L * 4096 * 4096);
    uint16_t* ao    = (uint16_t*)alloc(16384L * 512 * 2);
    if (off > ws_size) return;  // workspace too small -> fail visibly

    gn_stats<<<128, 256, 0, stream>>>(x, stats, lrow);
    gn_apply<<<8192, 256, 0, stream>>>(x, stats, gg, gb, h);
    wcast_transpose<<<dim3(8, 8, 4), 256, 0, stream>>>(wq, wk, wv, wp, wT);

    // q / k / v^T (fp8) in one dispatch
    qkv_gemm<<<dim3(12, 128), 256, 0, stream>>>(h, wT, bq, bk, bv, q8, k8, vt8);
    // p[b] = exp2(scale * q[b] @ k[b]^T) as fp8, row sums into lrow
    const float qscale = 0.06375871540654937f;   // log2(e)/sqrt(512)
    gemm_f8<3><<<dim3(32, 32, 4), 256, 0, stream>>>(q8, k8, sc8, lrow, qscale,
                                                    4096, 4096, 512,
                                                    4096L * 512, 4096L * 512, 4096L * 4096);
    // ao[b] = (p[b] @ v[b]) / l    (fp8 x fp8 -> bf16)
    gemm_f8<4><<<dim3(4, 32, 4), 256, 0, stream>>>(sc8, vt8, ao, lrow, 1.f,
                                                   4096, 512, 4096,
                                                   4096L * 4096, 512L * 4096, 4096L * 512);
    // out = x + ao @ wp + bp
    gemm_proj<<<dim3(4, 128), 256, 0, stream>>>(ao, wT + 3 * 262144, out, bp, x);
}